// Round 3
// baseline (114.537 us; speedup 1.0000x reference)
//
#include <hip/hip_runtime.h>
#include <hip/hip_bf16.h>
#include <math.h>

#define NROWS 4096
#define HD 512
#define HEADS 8
#define HDD 64
#define SEQ 1024
#define QSCALE 0.18033688011112042f   // 0.125 * log2(e)

typedef unsigned short u16;
typedef __attribute__((ext_vector_type(8))) short sh8;   // 8 bf16 (4 VGPRs)
typedef __attribute__((ext_vector_type(4))) float f4;    // MFMA accumulator

__device__ __forceinline__ f4 mfma16(sh8 a, sh8 b, f4 c) {
  return __builtin_amdgcn_mfma_f32_16x16x32_bf16(a, b, c, 0, 0, 0);
}

__device__ __forceinline__ u16 f2bf(float x) {
  union { float f; unsigned u; } v; v.f = x;
  unsigned r = v.u + 0x7fff + ((v.u >> 16) & 1);   // RNE
  return (u16)(r >> 16);
}

// XOR swizzles: spread same-column ds_read_b128 across 8 distinct 16B slots.
#define SWZA(r, cb) ((((r) * 128) + (cb)) ^ (((r) & 7) << 4))   // 128B rows
#define SWZB(r, cb) ((((r) * 256) + (cb)) ^ (((r) & 7) << 4))   // 256B rows

// ---------------- quantum gate helpers (register statevector) ----------------
template<int M>
__device__ __forceinline__ void g_rx(float* sr, float* si, float c, float s) {
#pragma unroll
  for (int a = 0; a < 16; ++a) if (!(a & M)) {
    const int b = a | M;
    float ar = sr[a], ai = si[a], br = sr[b], bi = si[b];
    sr[a] = c*ar + s*bi;  si[a] = c*ai - s*br;
    sr[b] = c*br + s*ai;  si[b] = c*bi - s*ar;
  }
}

template<int M>
__device__ __forceinline__ void g_ry(float* sr, float* si, float c, float s) {
#pragma unroll
  for (int a = 0; a < 16; ++a) if (!(a & M)) {
    const int b = a | M;
    float ar = sr[a], ai = si[a], br = sr[b], bi = si[b];
    sr[a] = c*ar - s*br;  si[a] = c*ai - s*bi;
    sr[b] = s*ar + c*br;  si[b] = s*ai + c*bi;
  }
}

template<int M>
__device__ __forceinline__ void g_rz(float* sr, float* si, float c, float s) {
#pragma unroll
  for (int a = 0; a < 16; ++a) if (!(a & M)) {
    const int b = a | M;
    float ar = sr[a], ai = si[a];
    sr[a] = c*ar + s*ai;  si[a] = c*ai - s*ar;
    float br = sr[b], bi = si[b];
    sr[b] = c*br - s*bi;  si[b] = c*bi + s*br;
  }
}

template<int MC, int MT>
__device__ __forceinline__ void g_crx(float* sr, float* si, float c, float s) {
#pragma unroll
  for (int a = 0; a < 16; ++a) if ((a & MC) && !(a & MT)) {
    const int b = a | MT;
    float ar = sr[a], ai = si[a], br = sr[b], bi = si[b];
    sr[a] = c*ar + s*bi;  si[a] = c*ai - s*br;
    sr[b] = c*br + s*ai;  si[b] = c*bi - s*ar;
  }
}

// ---------------- K1: p = LN(tanh(x @ Wp^T + bp)) ----------------
__global__ __launch_bounds__(256) void k_proj_ln(const float* __restrict__ x,
    const float* __restrict__ Wp, const float* __restrict__ bp,
    const float* __restrict__ g, const float* __restrict__ b,
    float* __restrict__ p) {
  int row  = blockIdx.x * 4 + (threadIdx.x >> 6);
  int lane = threadIdx.x & 63;
  const float* xr = x + row * HD + lane * 8;
  float4 xa = *(const float4*)xr;
  float4 xb = *(const float4*)(xr + 4);
  float acc[4];
#pragma unroll
  for (int j = 0; j < 4; ++j) {
    const float* wr = Wp + j * HD + lane * 8;
    float4 wa = *(const float4*)wr;
    float4 wb = *(const float4*)(wr + 4);
    acc[j] = xa.x*wa.x + xa.y*wa.y + xa.z*wa.z + xa.w*wa.w
           + xb.x*wb.x + xb.y*wb.y + xb.z*wb.z + xb.w*wb.w;
  }
#pragma unroll
  for (int j = 0; j < 4; ++j) {
#pragma unroll
    for (int off = 32; off >= 1; off >>= 1)
      acc[j] += __shfl_xor(acc[j], off);
  }
  if (lane == 0) {
    float v0 = tanhf(acc[0] + bp[0]);
    float v1 = tanhf(acc[1] + bp[1]);
    float v2 = tanhf(acc[2] + bp[2]);
    float v3 = tanhf(acc[3] + bp[3]);
    float mu = 0.25f * (v0 + v1 + v2 + v3);
    float d0 = v0 - mu, d1 = v1 - mu, d2 = v2 - mu, d3 = v3 - mu;
    float inv = rsqrtf(0.25f * (d0*d0 + d1*d1 + d2*d2 + d3*d3) + 1e-5f);
    *(float4*)(p + row * 4) = make_float4(d0*inv*g[0] + b[0], d1*inv*g[1] + b[1],
                                          d2*inv*g[2] + b[2], d3*inv*g[3] + b[3]);
  }
}

// ---------------- K2a: precompute M[c][j][16][16] quadratic-form matrices ----
// psi_final = U psi0 (psi0 real). t[c][j] = psi0^T Re(U^H P_j U) psi0.
__global__ __launch_bounds__(256) void k_prep(
    const float* __restrict__ qw, const float* __restrict__ qe,
    const float* __restrict__ qg, const float* __restrict__ qb,
    const float* __restrict__ kw, const float* __restrict__ ke,
    const float* __restrict__ kg, const float* __restrict__ kb,
    const float* __restrict__ vw, const float* __restrict__ ve,
    const float* __restrict__ vg, const float* __restrict__ vb,
    float* __restrict__ Mout) {
  __shared__ float angC[3][32], angS[3][32];
  __shared__ float Ur[3][16][16], Ui[3][16][16];
  const int tid = threadIdx.x;

  // phase 0: sincos of all 30 half-angles per circuit
  if (tid < 90) {
    int c = tid / 30, ai = tid - c * 30;
    const float* w = (c == 0) ? qw : (c == 1) ? kw : vw;
    const float* e = (c == 0) ? qe : (c == 1) ? ke : ve;
    const float* g = (c == 0) ? qg : (c == 1) ? kg : vg;
    const float* b = (c == 0) ? qb : (c == 1) ? kb : vb;
    float ang = (ai < 12) ? w[ai] : (ai < 24) ? e[ai - 12]
               : (ai < 27) ? g[ai - 24] : b[ai - 27];
    float s_, c_;
    sincosf(0.5f * ang, &s_, &c_);
    angC[c][ai] = c_; angS[c][ai] = s_;
  }
  __syncthreads();

  // phase 1: simulate fixed circuit on each basis column -> U
  if (tid < 48) {
    int c = tid >> 4, col = tid & 15;
    float sr[16], si[16];
#pragma unroll
    for (int a = 0; a < 16; ++a) { sr[a] = (a == col) ? 1.f : 0.f; si[a] = 0.f; }
    for (int L = 0; L < 3; ++L) {
      { float cc = angC[c][L*4+0], ss = angS[c][L*4+0];
        g_rx<8>(sr,si,cc,ss); g_ry<8>(sr,si,cc,ss); g_rz<8>(sr,si,cc,ss); }
      { float cc = angC[c][L*4+1], ss = angS[c][L*4+1];
        g_rx<4>(sr,si,cc,ss); g_ry<4>(sr,si,cc,ss); g_rz<4>(sr,si,cc,ss); }
      { float cc = angC[c][L*4+2], ss = angS[c][L*4+2];
        g_rx<2>(sr,si,cc,ss); g_ry<2>(sr,si,cc,ss); g_rz<2>(sr,si,cc,ss); }
      { float cc = angC[c][L*4+3], ss = angS[c][L*4+3];
        g_rx<1>(sr,si,cc,ss); g_ry<1>(sr,si,cc,ss); g_rz<1>(sr,si,cc,ss); }
      g_crx<8,4>(sr, si, angC[c][12+L*4+0], angS[c][12+L*4+0]);
      g_crx<4,2>(sr, si, angC[c][12+L*4+1], angS[c][12+L*4+1]);
      g_crx<2,1>(sr, si, angC[c][12+L*4+2], angS[c][12+L*4+2]);
      g_crx<1,8>(sr, si, angC[c][12+L*4+3], angS[c][12+L*4+3]);
      // Grover diffusion == I - 2|s><s|  =>  psi -= (sum psi)/8
      { float sR = 0.f, sI = 0.f;
#pragma unroll
        for (int a = 0; a < 16; ++a) { sR += sr[a]; sI += si[a]; }
        sR *= 0.125f; sI *= 0.125f;
#pragma unroll
        for (int a = 0; a < 16; ++a) { sr[a] -= sR; si[a] -= sI; } }
      // QAOA cost: product of exp(+-i gam/2) over adjacent-qubit pairs
      { float cg = angC[c][24+L], sg = angS[c][24+L];
        float c2 = cg*cg - sg*sg, s2 = 2.f*cg*sg;
        float c3 = cg*c2 - sg*s2, s3 = cg*s2 + sg*c2;
#pragma unroll
        for (int a = 0; a < 16; ++a) {
          const int u = (a ^ (a >> 1)) & 7;
          const int n = (u & 1) + ((u >> 1) & 1) + ((u >> 2) & 1);
          const float pc = (n == 0 || n == 3) ? c3 : cg;
          const float ps = (n == 0) ? -s3 : (n == 1) ? -sg : (n == 2) ? sg : s3;
          float r = sr[a], im = si[a];
          sr[a] = r * pc - im * ps;
          si[a] = r * ps + im * pc;
        } }
      // mixer RX(bet) on all qubits
      { float cb_ = angC[c][27+L], sb_ = angS[c][27+L];
        g_rx<8>(sr,si,cb_,sb_); g_rx<4>(sr,si,cb_,sb_);
        g_rx<2>(sr,si,cb_,sb_); g_rx<1>(sr,si,cb_,sb_); }
    }
#pragma unroll
    for (int k = 0; k < 16; ++k) { Ur[c][k][col] = sr[k]; Ui[c][k][col] = si[k]; }
  }
  __syncthreads();

  // phase 2: M[c][j][a][b] = Re( sum_k conj(U[k][a]) (P_j U)[k][b] )
  for (int e = tid; e < 576; e += 256) {
    int c = e / 192, r0 = e - c * 192, j = r0 >> 4, a = r0 & 15;
    int typ = j >> 2;                 // 0=Z 1=X 2=Y
    int Mm = 8 >> (j & 3);
    float ax[4] = {0.f, 0.f, 0.f, 0.f}, ay[4] = {0.f, 0.f, 0.f, 0.f},
          az[4] = {0.f, 0.f, 0.f, 0.f}, aw[4] = {0.f, 0.f, 0.f, 0.f};
#pragma unroll
    for (int k = 0; k < 16; ++k) {
      float uar = Ur[c][k][a], uai = Ui[c][k][a];
      int k2; float cR, cI;
      if (typ == 0)      { k2 = k;      float z = (k & Mm) ? -1.f : 1.f; cR = z*uar; cI = z*uai; }
      else if (typ == 1) { k2 = k ^ Mm; cR = uar; cI = uai; }
      else               { k2 = k ^ Mm; float sg = (k & Mm) ? 1.f : -1.f; cR = sg*uai; cI = -sg*uar; }
      const float* ur2 = Ur[c][k2];
      const float* ui2 = Ui[c][k2];
#pragma unroll
      for (int i = 0; i < 4; ++i) {
        ax[i] += cR * ur2[i*4+0] + cI * ui2[i*4+0];
        ay[i] += cR * ur2[i*4+1] + cI * ui2[i*4+1];
        az[i] += cR * ur2[i*4+2] + cI * ui2[i*4+2];
        aw[i] += cR * ur2[i*4+3] + cI * ui2[i*4+3];
      }
    }
    float* dst = Mout + ((c * 12 + j) * 16 + a) * 16;
#pragma unroll
    for (int i = 0; i < 4; ++i)
      ((float4*)dst)[i] = make_float4(ax[i], ay[i], az[i], aw[i]);
  }
}

// ---------------- K2b: t[c][row][12] via quadratic forms ----------------
__global__ __launch_bounds__(64) void k_tvals(const float* __restrict__ p,
    const float* __restrict__ Mg, float* __restrict__ t) {
  const int c = blockIdx.x % 3, rb = blockIdx.x / 3;
  const int tid = threadIdx.x;
  const int row = rb * 64 + tid;
  __shared__ float Ml[3072];
  const float4* src = (const float4*)(Mg + c * 3072);
#pragma unroll
  for (int i = 0; i < 12; ++i)
    ((float4*)Ml)[tid + i * 64] = src[tid + i * 64];
  __syncthreads();

  float4 in4 = *(const float4*)(p + row * 4);
  float cs[4], sn[4];
  sincosf(0.5f * in4.x, &sn[0], &cs[0]);
  sincosf(0.5f * in4.y, &sn[1], &cs[1]);
  sincosf(0.5f * in4.z, &sn[2], &cs[2]);
  sincosf(0.5f * in4.w, &sn[3], &cs[3]);
  float q01[4] = {cs[0]*cs[1], cs[0]*sn[1], sn[0]*cs[1], sn[0]*sn[1]};
  float q23[4] = {cs[2]*cs[3], cs[2]*sn[3], sn[2]*cs[3], sn[2]*sn[3]};
  float psi[16];
#pragma unroll
  for (int a = 0; a < 16; ++a) psi[a] = q01[a >> 2] * q23[a & 3];

  float* to = t + (c * NROWS + row) * 12;
  for (int j = 0; j < 12; ++j) {
    const float* Mj = Ml + j * 256;
    float y = 0.f;
#pragma unroll
    for (int a = 0; a < 16; ++a) {
      const float4* mr = (const float4*)(Mj + a * 16);
      float rsum = 0.f;
#pragma unroll
      for (int i = 0; i < 4; ++i) {
        float4 m4 = mr[i];
        rsum += m4.x*psi[i*4] + m4.y*psi[i*4+1] + m4.z*psi[i*4+2] + m4.w*psi[i*4+3];
      }
      y += psi[a] * rsum;
    }
    to[j] = y;
  }
}

// -------- K3: q/k/v = t @ W^T + b -> bf16; Q scaled; V transposed [bh][64][s]
__global__ __launch_bounds__(256) void k_qkvproj(const float* __restrict__ t,
    const float* __restrict__ Wq, const float* __restrict__ bq,
    const float* __restrict__ Wk, const float* __restrict__ bk,
    const float* __restrict__ Wv, const float* __restrict__ bv,
    u16* __restrict__ Qo, u16* __restrict__ Ko, u16* __restrict__ Vto) {
  int n = blockIdx.x;
  int tid = threadIdx.x;
  __shared__ float tt[3][12];
  if (tid < 36) {
    int cc = tid / 12, j = tid - cc * 12;
    tt[cc][j] = t[(cc * NROWS + n) * 12 + j];
  }
  __syncthreads();
  int bb = n >> 10, ss = n & 1023;
  for (int o = tid; o < HD; o += 256) {
    int h = o >> 6, d = o & 63;
    float aq = bq[o], ak = bk[o], av = bv[o];
#pragma unroll
    for (int j = 0; j < 12; ++j) {
      aq += tt[0][j] * Wq[o * 12 + j];
      ak += tt[1][j] * Wk[o * 12 + j];
      av += tt[2][j] * Wv[o * 12 + j];
    }
    int bhh = bb * HEADS + h;
    Qo[(bhh * SEQ + ss) * HDD + d] = f2bf(aq * QSCALE);
    Ko[(bhh * SEQ + ss) * HDD + d] = f2bf(ak);
    Vto[(bhh * HDD + d) * SEQ + ss] = f2bf(av);
  }
}

// ---------------- K4: MFMA flash attention, max-free softmax ----------------
// grid (16 qtiles, 32 bh); 4 waves; wave owns 16 q-rows; KV chunk 128.
__global__ __launch_bounds__(256) void k_attn_mfma(const u16* __restrict__ Q,
    const u16* __restrict__ K, const u16* __restrict__ Vt,
    u16* __restrict__ Ob) {
  const int bh = blockIdx.y, qt = blockIdx.x;
  const int tid = threadIdx.x, w = tid >> 6, l = tid & 63;
  const int lr = l & 15, lh = l >> 4;

  __shared__ u16 Kl[128 * 64];       // [key][d]   swizzled, 128B rows
  __shared__ u16 Vl[64 * 128];       // [d][key]   swizzled, 256B rows
  __shared__ u16 Pl[4][16 * 128];    // per-wave [q][key] swizzled, 256B rows

  const u16* Qb = Q + (bh * SEQ + qt * 64) * HDD;
  const u16* Kb = K + bh * SEQ * HDD;
  const u16* Vb = Vt + bh * HDD * SEQ;

  sh8 qf[2];
#pragma unroll
  for (int kk = 0; kk < 2; ++kk)
    qf[kk] = *(const sh8*)(Qb + (w * 16 + lr) * HDD + kk * 32 + lh * 8);

  f4 oacc[4];
  float lsum[4] = {0.f, 0.f, 0.f, 0.f};
#pragma unroll
  for (int n = 0; n < 4; ++n) oacc[n] = (f4){0.f, 0.f, 0.f, 0.f};

  for (int ch = 0; ch < SEQ / 128; ++ch) {
    __syncthreads();                       // prev chunk fully consumed
#pragma unroll
    for (int i = 0; i < 4; ++i) {          // stage K 128x64
      int idx = i * 256 + tid;
      int r = idx >> 3, c8 = idx & 7;
      *(sh8*)((char*)Kl + SWZA(r, c8 * 16)) =
          *(const sh8*)(Kb + (ch * 128 + r) * HDD + c8 * 8);
    }
#pragma unroll
    for (int i = 0; i < 4; ++i) {          // stage V^T 64x128
      int idx = i * 256 + tid;
      int r = idx >> 4, c8 = idx & 15;
      *(sh8*)((char*)Vl + SWZB(r, c8 * 16)) =
          *(const sh8*)(Vb + r * SEQ + ch * 128 + c8 * 8);
    }
    __syncthreads();

    // S = Q K^T  (Q pre-scaled so S is already in log2 units)
    f4 sacc[8];
#pragma unroll
    for (int n = 0; n < 8; ++n) sacc[n] = (f4){0.f, 0.f, 0.f, 0.f};
#pragma unroll
    for (int kk = 0; kk < 2; ++kk) {
#pragma unroll
      for (int n = 0; n < 8; ++n) {
        sh8 kf = *(const sh8*)((const char*)Kl + SWZA(n * 16 + lr, kk * 64 + lh * 16));
        sacc[n] = mfma16(qf[kk], kf, sacc[n]);
      }
    }

    // P = 2^S, accumulate row partial sums, write P to per-wave LDS
#pragma unroll
    for (int n = 0; n < 8; ++n) {
#pragma unroll
      for (int r = 0; r < 4; ++r) {
        float pv = exp2f(sacc[n][r]);
        lsum[r] += pv;
        *(u16*)((char*)Pl[w] + SWZB(lh * 4 + r, (n * 16 + lr) * 2)) = f2bf(pv);
      }
    }
    // no barrier needed: Pl is per-wave, lgkmcnt ordering suffices

    // O += P V
#pragma unroll
    for (int kk = 0; kk < 4; ++kk) {
      sh8 pf = *(const sh8*)((const char*)Pl[w] + SWZB(lr, kk * 64 + lh * 16));
#pragma unroll
      for (int n = 0; n < 4; ++n) {
        sh8 vf = *(const sh8*)((const char*)Vl + SWZB(n * 16 + lr, kk * 64 + lh * 16));
        oacc[n] = mfma16(pf, vf, oacc[n]);
      }
    }
  }

  // final row-sum reduce across the 16-lane lr group (once per kernel)
#pragma unroll
  for (int r = 0; r < 4; ++r) {
    lsum[r] += __shfl_xor(lsum[r], 1); lsum[r] += __shfl_xor(lsum[r], 2);
    lsum[r] += __shfl_xor(lsum[r], 4); lsum[r] += __shfl_xor(lsum[r], 8);
  }

  int bb = bh >> 3, h = bh & 7;
#pragma unroll
  for (int r = 0; r < 4; ++r) {
    int row = qt * 64 + w * 16 + lh * 4 + r;
    float inv = 1.f / lsum[r];
#pragma unroll
    for (int n = 0; n < 4; ++n)
      Ob[(bb * SEQ + row) * HD + h * 64 + n * 16 + lr] = f2bf(oacc[n][r] * inv);
  }
}

// ---------------- K5: out = a @ Wo^T + bo (MFMA) ----------------
__global__ __launch_bounds__(256) void k_oproj_mfma(const u16* __restrict__ A,
    const u16* __restrict__ W, const float* __restrict__ bo,
    float* __restrict__ out) {
  const int nb = blockIdx.x, ob = blockIdx.y;
  const int tid = threadIdx.x, w = tid >> 6, l = tid & 63;
  const int lr = l & 15, lh = l >> 4;
  __shared__ u16 Al[64 * 64];
  __shared__ u16 Wl[64 * 64];
  f4 acc[4];
#pragma unroll
  for (int n = 0; n < 4; ++n) acc[n] = (f4){0.f, 0.f, 0.f, 0.f};
  for (int ch = 0; ch < 8; ++ch) {
    __syncthreads();
#pragma unroll
    for (int i = 0; i < 2; ++i) {
      int idx = i * 256 + tid;
      int r = idx >> 3, c8 = idx & 7;
      *(sh8*)((char*)Al + SWZA(r, c8 * 16)) =
          *(const sh8*)(A + (nb * 64 + r) * HD + ch * 64 + c8 * 8);
      *(sh8*)((char*)Wl + SWZA(r, c8 * 16)) =
          *(const sh8*)(W + (ob * 64 + r) * HD + ch * 64 + c8 * 8);
    }
    __syncthreads();
#pragma unroll
    for (int kk = 0; kk < 2; ++kk) {
      sh8 af = *(const sh8*)((const char*)Al + SWZA(w * 16 + lr, kk * 64 + lh * 16));
#pragma unroll
      for (int n = 0; n < 4; ++n) {
        sh8 wf = *(const sh8*)((const char*)Wl + SWZA(n * 16 + lr, kk * 64 + lh * 16));
        acc[n] = mfma16(af, wf, acc[n]);
      }
    }
  }
#pragma unroll
  for (int r = 0; r < 4; ++r) {
    int row = nb * 64 + w * 16 + lh * 4 + r;
#pragma unroll
    for (int n = 0; n < 4; ++n) {
      int col = ob * 64 + n * 16 + lr;
      out[row * HD + col] = acc[n][r] + bo[col];
    }
  }
}

// ---------------- K6: fp32 -> bf16 convert (Wo) ----------------
__global__ __launch_bounds__(256) void k_cvt(const float* __restrict__ in,
                                             u16* __restrict__ o, int n) {
  int i = (blockIdx.x * 256 + threadIdx.x) * 4;
  if (i < n) {
    float4 v = *(const float4*)(in + i);
    o[i]   = f2bf(v.x); o[i+1] = f2bf(v.y);
    o[i+2] = f2bf(v.z); o[i+3] = f2bf(v.w);
  }
}

// ---------------- launch ----------------
extern "C" void kernel_launch(void* const* d_in, const int* in_sizes, int n_in,
                              void* d_out, int out_size, void* d_ws, size_t ws_size,
                              hipStream_t stream) {
  const float* x    = (const float*)d_in[0];
  const float* Wp   = (const float*)d_in[1];
  const float* bp   = (const float*)d_in[2];
  const float* ln_g = (const float*)d_in[3];
  const float* ln_b = (const float*)d_in[4];
  const float* qw   = (const float*)d_in[5];
  const float* qe   = (const float*)d_in[6];
  const float* qg   = (const float*)d_in[7];
  const float* qb_  = (const float*)d_in[8];
  const float* kw   = (const float*)d_in[9];
  const float* ke   = (const float*)d_in[10];
  const float* kg   = (const float*)d_in[11];
  const float* kb_  = (const float*)d_in[12];
  const float* vw   = (const float*)d_in[13];
  const float* ve   = (const float*)d_in[14];
  const float* vg   = (const float*)d_in[15];
  const float* vb_  = (const float*)d_in[16];
  const float* Wq   = (const float*)d_in[17];
  const float* bq   = (const float*)d_in[18];
  const float* Wk   = (const float*)d_in[19];
  const float* bk   = (const float*)d_in[20];
  const float* Wv   = (const float*)d_in[21];
  const float* bv   = (const float*)d_in[22];
  const float* Wo   = (const float*)d_in[23];
  const float* bo   = (const float*)d_in[24];

  float* ws   = (float*)d_ws;
  float* pbuf = ws;                        // 16384 f
  float* tbuf = ws + 16384;                // 147456 f
  float* Mbuf = tbuf + 147456;             // 9216 f
  u16* qb  = (u16*)(Mbuf + 9216);          // 32*1024*64
  u16* kb  = qb + 32 * SEQ * HDD;
  u16* vtb = kb + 32 * SEQ * HDD;
  u16* ab  = vtb + 32 * SEQ * HDD;         // 4096*512
  u16* wob = ab + NROWS * HD;              // 512*512

  k_proj_ln<<<NROWS / 4, 256, 0, stream>>>(x, Wp, bp, ln_g, ln_b, pbuf);
  k_prep<<<1, 256, 0, stream>>>(qw, qe, qg, qb_, kw, ke, kg, kb_,
                                vw, ve, vg, vb_, Mbuf);
  k_tvals<<<192, 64, 0, stream>>>(pbuf, Mbuf, tbuf);
  k_qkvproj<<<NROWS, 256, 0, stream>>>(tbuf, Wq, bq, Wk, bk, Wv, bv,
                                       qb, kb, vtb);
  k_cvt<<<(HD * HD) / 1024, 256, 0, stream>>>(Wo, wob, HD * HD);
  dim3 ga(SEQ / 64, 32);
  k_attn_mfma<<<ga, 256, 0, stream>>>(qb, kb, vtb, ab);
  dim3 go(NROWS / 64, HD / 64);
  k_oproj_mfma<<<go, 256, 0, stream>>>(ab, wob, bo, (float*)d_out);
}

// Round 4
// 113.027 us; speedup vs baseline: 1.0134x; 1.0134x over previous
//
#include <hip/hip_runtime.h>
#include <hip/hip_bf16.h>
#include <math.h>

#define NROWS 4096
#define HD 512
#define HEADS 8
#define HDD 64
#define SEQ 1024
#define QSCALE 0.18033688011112042f   // 0.125 * log2(e)

typedef unsigned short u16;
typedef __attribute__((ext_vector_type(8))) short sh8;   // 8 bf16 (4 VGPRs)
typedef __attribute__((ext_vector_type(4))) float f4;    // MFMA accumulator

__device__ __forceinline__ f4 mfma16(sh8 a, sh8 b, f4 c) {
  return __builtin_amdgcn_mfma_f32_16x16x32_bf16(a, b, c, 0, 0, 0);
}

__device__ __forceinline__ u16 f2bf(float x) {
  union { float f; unsigned u; } v; v.f = x;
  unsigned r = v.u + 0x7fff + ((v.u >> 16) & 1);   // RNE
  return (u16)(r >> 16);
}

// XOR swizzles: spread same-column ds_read_b128 across 8 distinct 16B slots.
#define SWZA(r, cb) ((((r) * 128) + (cb)) ^ (((r) & 7) << 4))   // 128B rows
#define SWZB(r, cb) ((((r) * 256) + (cb)) ^ (((r) & 7) << 4))   // 256B rows

// ---------------- quantum gate helpers (register statevector) ----------------
template<int M>
__device__ __forceinline__ void g_rx(float* sr, float* si, float c, float s) {
#pragma unroll
  for (int a = 0; a < 16; ++a) if (!(a & M)) {
    const int b = a | M;
    float ar = sr[a], ai = si[a], br = sr[b], bi = si[b];
    sr[a] = c*ar + s*bi;  si[a] = c*ai - s*br;
    sr[b] = c*br + s*ai;  si[b] = c*bi - s*ar;
  }
}

template<int M>
__device__ __forceinline__ void g_ry(float* sr, float* si, float c, float s) {
#pragma unroll
  for (int a = 0; a < 16; ++a) if (!(a & M)) {
    const int b = a | M;
    float ar = sr[a], ai = si[a], br = sr[b], bi = si[b];
    sr[a] = c*ar - s*br;  si[a] = c*ai - s*bi;
    sr[b] = s*ar + c*br;  si[b] = s*ai + c*bi;
  }
}

template<int M>
__device__ __forceinline__ void g_rz(float* sr, float* si, float c, float s) {
#pragma unroll
  for (int a = 0; a < 16; ++a) if (!(a & M)) {
    const int b = a | M;
    float ar = sr[a], ai = si[a];
    sr[a] = c*ar + s*ai;  si[a] = c*ai - s*ar;
    float br = sr[b], bi = si[b];
    sr[b] = c*br - s*bi;  si[b] = c*bi + s*br;
  }
}

template<int MC, int MT>
__device__ __forceinline__ void g_crx(float* sr, float* si, float c, float s) {
#pragma unroll
  for (int a = 0; a < 16; ++a) if ((a & MC) && !(a & MT)) {
    const int b = a | MT;
    float ar = sr[a], ai = si[a], br = sr[b], bi = si[b];
    sr[a] = c*ar + s*bi;  si[a] = c*ai - s*br;
    sr[b] = c*br + s*ai;  si[b] = c*bi - s*ar;
  }
}

// ---------------- K1: p = LN(tanh(x @ Wp^T + bp)) ----------------
__global__ __launch_bounds__(256) void k_proj_ln(const float* __restrict__ x,
    const float* __restrict__ Wp, const float* __restrict__ bp,
    const float* __restrict__ g, const float* __restrict__ b,
    float* __restrict__ p) {
  int row  = blockIdx.x * 4 + (threadIdx.x >> 6);
  int lane = threadIdx.x & 63;
  const float* xr = x + row * HD + lane * 8;
  float4 xa = *(const float4*)xr;
  float4 xb = *(const float4*)(xr + 4);
  float acc[4];
#pragma unroll
  for (int j = 0; j < 4; ++j) {
    const float* wr = Wp + j * HD + lane * 8;
    float4 wa = *(const float4*)wr;
    float4 wb = *(const float4*)(wr + 4);
    acc[j] = xa.x*wa.x + xa.y*wa.y + xa.z*wa.z + xa.w*wa.w
           + xb.x*wb.x + xb.y*wb.y + xb.z*wb.z + xb.w*wb.w;
  }
#pragma unroll
  for (int j = 0; j < 4; ++j) {
#pragma unroll
    for (int off = 32; off >= 1; off >>= 1)
      acc[j] += __shfl_xor(acc[j], off);
  }
  if (lane == 0) {
    float v0 = tanhf(acc[0] + bp[0]);
    float v1 = tanhf(acc[1] + bp[1]);
    float v2 = tanhf(acc[2] + bp[2]);
    float v3 = tanhf(acc[3] + bp[3]);
    float mu = 0.25f * (v0 + v1 + v2 + v3);
    float d0 = v0 - mu, d1 = v1 - mu, d2 = v2 - mu, d3 = v3 - mu;
    float inv = rsqrtf(0.25f * (d0*d0 + d1*d1 + d2*d2 + d3*d3) + 1e-5f);
    *(float4*)(p + row * 4) = make_float4(d0*inv*g[0] + b[0], d1*inv*g[1] + b[1],
                                          d2*inv*g[2] + b[2], d3*inv*g[3] + b[3]);
  }
}

// ---------------- K2a: build U[c] (16x16 complex) -- one block per circuit ----
// U layout in global: U[c*512 + 0..255] = Re (k*16+col), U[c*512+256+..] = Im
__global__ __launch_bounds__(64) void k_prepU(
    const float* __restrict__ qw, const float* __restrict__ qe,
    const float* __restrict__ qg, const float* __restrict__ qb,
    const float* __restrict__ kw, const float* __restrict__ ke,
    const float* __restrict__ kg, const float* __restrict__ kb,
    const float* __restrict__ vw, const float* __restrict__ ve,
    const float* __restrict__ vg, const float* __restrict__ vb,
    float* __restrict__ Uout) {
  const int c = blockIdx.x;
  const int tid = threadIdx.x;
  __shared__ float angC[32], angS[32];
  const float* w = (c == 0) ? qw : (c == 1) ? kw : vw;
  const float* e = (c == 0) ? qe : (c == 1) ? ke : ve;
  const float* g = (c == 0) ? qg : (c == 1) ? kg : vg;
  const float* b = (c == 0) ? qb : (c == 1) ? kb : vb;
  if (tid < 30) {
    float ang = (tid < 12) ? w[tid] : (tid < 24) ? e[tid - 12]
               : (tid < 27) ? g[tid - 24] : b[tid - 27];
    float s_, c_;
    sincosf(0.5f * ang, &s_, &c_);
    angC[tid] = c_; angS[tid] = s_;
  }
  __syncthreads();

  if (tid < 16) {
    const int col = tid;
    float sr[16], si[16];
#pragma unroll
    for (int a = 0; a < 16; ++a) { sr[a] = (a == col) ? 1.f : 0.f; si[a] = 0.f; }
    for (int L = 0; L < 3; ++L) {
      { float cc = angC[L*4+0], ss = angS[L*4+0];
        g_rx<8>(sr,si,cc,ss); g_ry<8>(sr,si,cc,ss); g_rz<8>(sr,si,cc,ss); }
      { float cc = angC[L*4+1], ss = angS[L*4+1];
        g_rx<4>(sr,si,cc,ss); g_ry<4>(sr,si,cc,ss); g_rz<4>(sr,si,cc,ss); }
      { float cc = angC[L*4+2], ss = angS[L*4+2];
        g_rx<2>(sr,si,cc,ss); g_ry<2>(sr,si,cc,ss); g_rz<2>(sr,si,cc,ss); }
      { float cc = angC[L*4+3], ss = angS[L*4+3];
        g_rx<1>(sr,si,cc,ss); g_ry<1>(sr,si,cc,ss); g_rz<1>(sr,si,cc,ss); }
      g_crx<8,4>(sr, si, angC[12+L*4+0], angS[12+L*4+0]);
      g_crx<4,2>(sr, si, angC[12+L*4+1], angS[12+L*4+1]);
      g_crx<2,1>(sr, si, angC[12+L*4+2], angS[12+L*4+2]);
      g_crx<1,8>(sr, si, angC[12+L*4+3], angS[12+L*4+3]);
      // Grover diffusion == I - 2|s><s|  =>  psi -= (sum psi)/8
      { float sR = 0.f, sI = 0.f;
#pragma unroll
        for (int a = 0; a < 16; ++a) { sR += sr[a]; sI += si[a]; }
        sR *= 0.125f; sI *= 0.125f;
#pragma unroll
        for (int a = 0; a < 16; ++a) { sr[a] -= sR; si[a] -= sI; } }
      // QAOA cost: diagonal phases exp(-i*gam/2 * sum_pairs ZZ)
      { float cg = angC[24+L], sg = angS[24+L];
        float c2 = cg*cg - sg*sg, s2 = 2.f*cg*sg;
        float c3 = cg*c2 - sg*s2, s3 = cg*s2 + sg*c2;
#pragma unroll
        for (int a = 0; a < 16; ++a) {
          const int u = (a ^ (a >> 1)) & 7;
          const int n = (u & 1) + ((u >> 1) & 1) + ((u >> 2) & 1);
          const float pc = (n == 0 || n == 3) ? c3 : cg;
          const float ps = (n == 0) ? -s3 : (n == 1) ? -sg : (n == 2) ? sg : s3;
          float r = sr[a], im = si[a];
          sr[a] = r * pc - im * ps;
          si[a] = r * ps + im * pc;
        } }
      // mixer RX(bet) on all qubits
      { float cb_ = angC[27+L], sb_ = angS[27+L];
        g_rx<8>(sr,si,cb_,sb_); g_rx<4>(sr,si,cb_,sb_);
        g_rx<2>(sr,si,cb_,sb_); g_rx<1>(sr,si,cb_,sb_); }
    }
    float* Uc = Uout + c * 512;
#pragma unroll
    for (int k = 0; k < 16; ++k) {
      Uc[k * 16 + col]       = sr[k];
      Uc[256 + k * 16 + col] = si[k];
    }
  }
}

// ---------------- K2b: M[c][j][a][b] from U -- one block per circuit ----------
// M[c][j][a][b] = Re( sum_k conj(U[k][a]) (P_j U)[k][b] )
__global__ __launch_bounds__(192) void k_prepM(const float* __restrict__ U,
                                               float* __restrict__ Mout) {
  const int c = blockIdx.x;
  const int tid = threadIdx.x;          // 192 = 12 j x 16 a
  __shared__ float Ur[256], Ui[256];    // [k*16+col]
  const float* Uc = U + c * 512;
  for (int i = tid; i < 256; i += 192) {
    Ur[i] = Uc[i];
    Ui[i] = Uc[256 + i];
  }
  __syncthreads();

  const int j = tid >> 4, a = tid & 15;
  const int typ = j >> 2;               // 0=Z 1=X 2=Y
  const int Mm = 8 >> (j & 3);
  float ax[4] = {0.f,0.f,0.f,0.f}, ay[4] = {0.f,0.f,0.f,0.f},
        az[4] = {0.f,0.f,0.f,0.f}, aw[4] = {0.f,0.f,0.f,0.f};
#pragma unroll
  for (int k = 0; k < 16; ++k) {
    float uar = Ur[k * 16 + a], uai = Ui[k * 16 + a];
    int k2; float cR, cI;
    if (typ == 0)      { k2 = k;      float z = (k & Mm) ? -1.f : 1.f; cR = z*uar; cI = z*uai; }
    else if (typ == 1) { k2 = k ^ Mm; cR = uar; cI = uai; }
    else               { k2 = k ^ Mm; float sg = (k & Mm) ? 1.f : -1.f; cR = sg*uai; cI = -sg*uar; }
    const float* ur2 = Ur + k2 * 16;
    const float* ui2 = Ui + k2 * 16;
#pragma unroll
    for (int i = 0; i < 4; ++i) {
      ax[i] += cR * ur2[i*4+0] + cI * ui2[i*4+0];
      ay[i] += cR * ur2[i*4+1] + cI * ui2[i*4+1];
      az[i] += cR * ur2[i*4+2] + cI * ui2[i*4+2];
      aw[i] += cR * ur2[i*4+3] + cI * ui2[i*4+3];
    }
  }
  float* dst = Mout + ((c * 12 + j) * 16 + a) * 16;
#pragma unroll
  for (int i = 0; i < 4; ++i)
    ((float4*)dst)[i] = make_float4(ax[i], ay[i], az[i], aw[i]);
}

// ---------------- K2c: t[c][row][12] via quadratic forms ----------------
__global__ __launch_bounds__(64) void k_tvals(const float* __restrict__ p,
    const float* __restrict__ Mg, float* __restrict__ t) {
  const int c = blockIdx.x % 3, rb = blockIdx.x / 3;
  const int tid = threadIdx.x;
  const int row = rb * 64 + tid;
  __shared__ float Ml[3072];
  const float4* src = (const float4*)(Mg + c * 3072);
#pragma unroll
  for (int i = 0; i < 12; ++i)
    ((float4*)Ml)[tid + i * 64] = src[tid + i * 64];
  __syncthreads();

  float4 in4 = *(const float4*)(p + row * 4);
  float cs[4], sn[4];
  sincosf(0.5f * in4.x, &sn[0], &cs[0]);
  sincosf(0.5f * in4.y, &sn[1], &cs[1]);
  sincosf(0.5f * in4.z, &sn[2], &cs[2]);
  sincosf(0.5f * in4.w, &sn[3], &cs[3]);
  float q01[4] = {cs[0]*cs[1], cs[0]*sn[1], sn[0]*cs[1], sn[0]*sn[1]};
  float q23[4] = {cs[2]*cs[3], cs[2]*sn[3], sn[2]*cs[3], sn[2]*sn[3]};
  float psi[16];
#pragma unroll
  for (int a = 0; a < 16; ++a) psi[a] = q01[a >> 2] * q23[a & 3];

  float* to = t + (c * NROWS + row) * 12;
  for (int j = 0; j < 12; ++j) {
    const float* Mj = Ml + j * 256;
    float y = 0.f;
#pragma unroll
    for (int a = 0; a < 16; ++a) {
      const float4* mr = (const float4*)(Mj + a * 16);
      float rsum = 0.f;
#pragma unroll
      for (int i = 0; i < 4; ++i) {
        float4 m4 = mr[i];
        rsum += m4.x*psi[i*4] + m4.y*psi[i*4+1] + m4.z*psi[i*4+2] + m4.w*psi[i*4+3];
      }
      y += psi[a] * rsum;
    }
    to[j] = y;
  }
}

// -------- K3: q/k/v = t @ W^T + b -> bf16; Q scaled; V transposed [bh][64][s]
__global__ __launch_bounds__(256) void k_qkvproj(const float* __restrict__ t,
    const float* __restrict__ Wq, const float* __restrict__ bq,
    const float* __restrict__ Wk, const float* __restrict__ bk,
    const float* __restrict__ Wv, const float* __restrict__ bv,
    u16* __restrict__ Qo, u16* __restrict__ Ko, u16* __restrict__ Vto) {
  int n = blockIdx.x;
  int tid = threadIdx.x;
  __shared__ float tt[3][12];
  if (tid < 36) {
    int cc = tid / 12, j = tid - cc * 12;
    tt[cc][j] = t[(cc * NROWS + n) * 12 + j];
  }
  __syncthreads();
  int bb = n >> 10, ss = n & 1023;
  for (int o = tid; o < HD; o += 256) {
    int h = o >> 6, d = o & 63;
    float aq = bq[o], ak = bk[o], av = bv[o];
#pragma unroll
    for (int j = 0; j < 12; ++j) {
      aq += tt[0][j] * Wq[o * 12 + j];
      ak += tt[1][j] * Wk[o * 12 + j];
      av += tt[2][j] * Wv[o * 12 + j];
    }
    int bhh = bb * HEADS + h;
    Qo[(bhh * SEQ + ss) * HDD + d] = f2bf(aq * QSCALE);
    Ko[(bhh * SEQ + ss) * HDD + d] = f2bf(ak);
    Vto[(bhh * HDD + d) * SEQ + ss] = f2bf(av);
  }
}

// ---------------- K4: MFMA flash attention, max-free softmax ----------------
// grid (16 qtiles, 32 bh); 4 waves; wave owns 16 q-rows; KV chunk 128.
__global__ __launch_bounds__(256) void k_attn_mfma(const u16* __restrict__ Q,
    const u16* __restrict__ K, const u16* __restrict__ Vt,
    u16* __restrict__ Ob) {
  const int bh = blockIdx.y, qt = blockIdx.x;
  const int tid = threadIdx.x, w = tid >> 6, l = tid & 63;
  const int lr = l & 15, lh = l >> 4;

  __shared__ u16 Kl[128 * 64];       // [key][d]   swizzled, 128B rows
  __shared__ u16 Vl[64 * 128];       // [d][key]   swizzled, 256B rows
  __shared__ u16 Pl[4][16 * 128];    // per-wave [q][key] swizzled, 256B rows

  const u16* Qb = Q + (bh * SEQ + qt * 64) * HDD;
  const u16* Kb = K + bh * SEQ * HDD;
  const u16* Vb = Vt + bh * HDD * SEQ;

  sh8 qf[2];
#pragma unroll
  for (int kk = 0; kk < 2; ++kk)
    qf[kk] = *(const sh8*)(Qb + (w * 16 + lr) * HDD + kk * 32 + lh * 8);

  f4 oacc[4];
  float lsum[4] = {0.f, 0.f, 0.f, 0.f};
#pragma unroll
  for (int n = 0; n < 4; ++n) oacc[n] = (f4){0.f, 0.f, 0.f, 0.f};

  for (int ch = 0; ch < SEQ / 128; ++ch) {
    __syncthreads();                       // prev chunk fully consumed
#pragma unroll
    for (int i = 0; i < 4; ++i) {          // stage K 128x64
      int idx = i * 256 + tid;
      int r = idx >> 3, c8 = idx & 7;
      *(sh8*)((char*)Kl + SWZA(r, c8 * 16)) =
          *(const sh8*)(Kb + (ch * 128 + r) * HDD + c8 * 8);
    }
#pragma unroll
    for (int i = 0; i < 4; ++i) {          // stage V^T 64x128
      int idx = i * 256 + tid;
      int r = idx >> 4, c8 = idx & 15;
      *(sh8*)((char*)Vl + SWZB(r, c8 * 16)) =
          *(const sh8*)(Vb + r * SEQ + ch * 128 + c8 * 8);
    }
    __syncthreads();

    // S = Q K^T  (Q pre-scaled so S is already in log2 units)
    f4 sacc[8];
#pragma unroll
    for (int n = 0; n < 8; ++n) sacc[n] = (f4){0.f, 0.f, 0.f, 0.f};
#pragma unroll
    for (int kk = 0; kk < 2; ++kk) {
#pragma unroll
      for (int n = 0; n < 8; ++n) {
        sh8 kf = *(const sh8*)((const char*)Kl + SWZA(n * 16 + lr, kk * 64 + lh * 16));
        sacc[n] = mfma16(qf[kk], kf, sacc[n]);
      }
    }

    // P = 2^S, accumulate row partial sums, write P to per-wave LDS
#pragma unroll
    for (int n = 0; n < 8; ++n) {
#pragma unroll
      for (int r = 0; r < 4; ++r) {
        float pv = exp2f(sacc[n][r]);
        lsum[r] += pv;
        *(u16*)((char*)Pl[w] + SWZB(lh * 4 + r, (n * 16 + lr) * 2)) = f2bf(pv);
      }
    }
    // no barrier needed: Pl is per-wave, lgkmcnt ordering suffices

    // O += P V
#pragma unroll
    for (int kk = 0; kk < 4; ++kk) {
      sh8 pf = *(const sh8*)((const char*)Pl[w] + SWZB(lr, kk * 64 + lh * 16));
#pragma unroll
      for (int n = 0; n < 4; ++n) {
        sh8 vf = *(const sh8*)((const char*)Vl + SWZB(n * 16 + lr, kk * 64 + lh * 16));
        oacc[n] = mfma16(pf, vf, oacc[n]);
      }
    }
  }

  // final row-sum reduce across the 16-lane lr group (once per kernel)
#pragma unroll
  for (int r = 0; r < 4; ++r) {
    lsum[r] += __shfl_xor(lsum[r], 1); lsum[r] += __shfl_xor(lsum[r], 2);
    lsum[r] += __shfl_xor(lsum[r], 4); lsum[r] += __shfl_xor(lsum[r], 8);
  }

  int bb = bh >> 3, h = bh & 7;
#pragma unroll
  for (int r = 0; r < 4; ++r) {
    int row = qt * 64 + w * 16 + lh * 4 + r;
    float inv = 1.f / lsum[r];
#pragma unroll
    for (int n = 0; n < 4; ++n)
      Ob[(bb * SEQ + row) * HD + h * 64 + n * 16 + lr] = f2bf(oacc[n][r] * inv);
  }
}

// ---------------- K5: out = a @ Wo^T + bo (MFMA) ----------------
__global__ __launch_bounds__(256) void k_oproj_mfma(const u16* __restrict__ A,
    const u16* __restrict__ W, const float* __restrict__ bo,
    float* __restrict__ out) {
  const int nb = blockIdx.x, ob = blockIdx.y;
  const int tid = threadIdx.x, w = tid >> 6, l = tid & 63;
  const int lr = l & 15, lh = l >> 4;
  __shared__ u16 Al[64 * 64];
  __shared__ u16 Wl[64 * 64];
  f4 acc[4];
#pragma unroll
  for (int n = 0; n < 4; ++n) acc[n] = (f4){0.f, 0.f, 0.f, 0.f};
  for (int ch = 0; ch < 8; ++ch) {
    __syncthreads();
#pragma unroll
    for (int i = 0; i < 2; ++i) {
      int idx = i * 256 + tid;
      int r = idx >> 3, c8 = idx & 7;
      *(sh8*)((char*)Al + SWZA(r, c8 * 16)) =
          *(const sh8*)(A + (nb * 64 + r) * HD + ch * 64 + c8 * 8);
      *(sh8*)((char*)Wl + SWZA(r, c8 * 16)) =
          *(const sh8*)(W + (ob * 64 + r) * HD + ch * 64 + c8 * 8);
    }
    __syncthreads();
#pragma unroll
    for (int kk = 0; kk < 2; ++kk) {
      sh8 af = *(const sh8*)((const char*)Al + SWZA(w * 16 + lr, kk * 64 + lh * 16));
#pragma unroll
      for (int n = 0; n < 4; ++n) {
        sh8 wf = *(const sh8*)((const char*)Wl + SWZA(n * 16 + lr, kk * 64 + lh * 16));
        acc[n] = mfma16(af, wf, acc[n]);
      }
    }
  }
#pragma unroll
  for (int r = 0; r < 4; ++r) {
    int row = nb * 64 + w * 16 + lh * 4 + r;
#pragma unroll
    for (int n = 0; n < 4; ++n) {
      int col = ob * 64 + n * 16 + lr;
      out[row * HD + col] = acc[n][r] + bo[col];
    }
  }
}

// ---------------- K6: fp32 -> bf16 convert (Wo) ----------------
__global__ __launch_bounds__(256) void k_cvt(const float* __restrict__ in,
                                             u16* __restrict__ o, int n) {
  int i = (blockIdx.x * 256 + threadIdx.x) * 4;
  if (i < n) {
    float4 v = *(const float4*)(in + i);
    o[i]   = f2bf(v.x); o[i+1] = f2bf(v.y);
    o[i+2] = f2bf(v.z); o[i+3] = f2bf(v.w);
  }
}

// ---------------- launch ----------------
extern "C" void kernel_launch(void* const* d_in, const int* in_sizes, int n_in,
                              void* d_out, int out_size, void* d_ws, size_t ws_size,
                              hipStream_t stream) {
  const float* x    = (const float*)d_in[0];
  const float* Wp   = (const float*)d_in[1];
  const float* bp   = (const float*)d_in[2];
  const float* ln_g = (const float*)d_in[3];
  const float* ln_b = (const float*)d_in[4];
  const float* qw   = (const float*)d_in[5];
  const float* qe   = (const float*)d_in[6];
  const float* qg   = (const float*)d_in[7];
  const float* qb_  = (const float*)d_in[8];
  const float* kw   = (const float*)d_in[9];
  const float* ke   = (const float*)d_in[10];
  const float* kg   = (const float*)d_in[11];
  const float* kb_  = (const float*)d_in[12];
  const float* vw   = (const float*)d_in[13];
  const float* ve   = (const float*)d_in[14];
  const float* vg   = (const float*)d_in[15];
  const float* vb_  = (const float*)d_in[16];
  const float* Wq   = (const float*)d_in[17];
  const float* bq   = (const float*)d_in[18];
  const float* Wk   = (const float*)d_in[19];
  const float* bk   = (const float*)d_in[20];
  const float* Wv   = (const float*)d_in[21];
  const float* bv   = (const float*)d_in[22];
  const float* Wo   = (const float*)d_in[23];
  const float* bo   = (const float*)d_in[24];

  float* ws   = (float*)d_ws;
  float* pbuf = ws;                        // 16384 f
  float* tbuf = ws + 16384;                // 147456 f
  float* Mbuf = tbuf + 147456;             // 9216 f
  float* Ubuf = Mbuf + 9216;               // 1536 f
  u16* qb  = (u16*)(Ubuf + 1536);          // 32*1024*64
  u16* kb  = qb + 32 * SEQ * HDD;
  u16* vtb = kb + 32 * SEQ * HDD;
  u16* ab  = vtb + 32 * SEQ * HDD;         // 4096*512
  u16* wob = ab + NROWS * HD;              // 512*512

  k_prepU<<<3, 64, 0, stream>>>(qw, qe, qg, qb_, kw, ke, kg, kb_,
                                vw, ve, vg, vb_, Ubuf);
  k_prepM<<<3, 192, 0, stream>>>(Ubuf, Mbuf);
  k_proj_ln<<<NROWS / 4, 256, 0, stream>>>(x, Wp, bp, ln_g, ln_b, pbuf);
  k_tvals<<<192, 64, 0, stream>>>(pbuf, Mbuf, tbuf);
  k_qkvproj<<<NROWS, 256, 0, stream>>>(tbuf, Wq, bq, Wk, bk, Wv, bv,
                                       qb, kb, vtb);
  k_cvt<<<(HD * HD) / 1024, 256, 0, stream>>>(Wo, wob, HD * HD);
  dim3 ga(SEQ / 64, 32);
  k_attn_mfma<<<ga, 256, 0, stream>>>(qb, kb, vtb, ab);
  dim3 go(NROWS / 64, HD / 64);
  k_oproj_mfma<<<go, 256, 0, stream>>>(ab, wob, bo, (float*)d_out);
}